// Round 1
// 137.325 us; speedup vs baseline: 1.0347x; 1.0347x over previous
//
#include <hip/hip_runtime.h>

// LSTM(units=64) over T=5, D_IN=1, then Dense(1, relu).
// R14 = R13 + paired-rcp merge + CSC-folded cell state.
// CHAMPION structure (93.0us rocprof best at R13): MB=128 column partition,
// wave w owns gate-cols [w*16,w*16+16) of all 4 gates, U B-fragments
// register-resident (asm-pinned vs remat), barriers between timesteps,
// gates in packed-fp32 (v_pk_*) exp2 + merged-rcp algebra:
//   p=(1+ei)(1+eg), q=(1+ef):  c' = (c*p + q*(1-eg)) * rcp(p*q)
//   h = o*tanh(c') = (1-ec) * rcp((1+eo)(1+ec)),  ec = exp2(-2L*c')
// R14 changes (trans-pipe reduction, both counters-predicted):
//  (a) rcp2: {1/a,1/b} = r*b, r*a with r=rcp(a*b) -- one v_rcp per f32x2
//      pair instead of two, at both sites. Overflow HARD-safe: |z|<=14
//      absolute (x*w<=7.5, h*u<=6.4, b=0) => pq<=1.3e18, pair<=1.7e36;
//      dn<=2.4e10, pair<=6e20. Error ~2ulp f32, invisible under f16 h.
//  (b) state carried as cs = CSC*c (CSC=-2*log2 e): num rewritten in
//      cs-terms via w = fma(eg,-CSC,CSC) = CSC*(1-eg); cs' = (cs*p+q*w)
//      *ipq feeds exp2 directly -- kills the separate sc=cn*CSC mul.
// Trans ops/cell: 7 -> 6 (t>=1), 6 -> 5 (t=0): 5.9e8 -> 5.0e8 (-14.7%).
// Optimization survey (R1-R13), all counters-verified:
//  - remat fix + exp2 algebra:  133 -> 102us   (R2-R4)
//  - packed fp32 cell-pairs:    102 -> 95.8us  (R8)
//  - block fatness parabola: MB 64/128/256 = 95.8/93.0/109 (R9/R11)
//  - occupancy: PINNED ~3 waves/SIMD by unified VGPR+AGPR file;
//    launch_bounds caps either no-op (R7) or spill (R6)
//  - barrier-free row partition: regressed 104us (R10) -- MFMA operands
//    must stay in registers
//  - software exp2 (deg-5 Taylor): regressed 147us (R12) -- hw trans
//    is ~2x cheaper in issue terms than packed-FMA emulation
// Falsification branch: if dur flat & VALUBusy ~72%+, kernel is
// VALU-issue-bound -> next: fold x*W+b seeding into a 3rd MFMA.
// absmax: exactly 1.953125e-3 (f16 h round-trip quantization).

typedef _Float16 f16x8 __attribute__((ext_vector_type(8)));
typedef float f32x4 __attribute__((ext_vector_type(4)));
typedef float f32x2 __attribute__((ext_vector_type(2)));

#define MB 128       // rows per block (2 groups of 64)
#define NTHREADS 256
#define HSTR 68

__device__ __forceinline__ float ex2(float x) { return __builtin_amdgcn_exp2f(x); }
__device__ __forceinline__ float rcp(float x) { return __builtin_amdgcn_rcpf(x); }
__device__ __forceinline__ f32x2 fma2(f32x2 a, f32x2 b, f32x2 c) {
    return __builtin_elementwise_fma(a, b, c);
}
// paired reciprocal: {1/x, 1/y} from ONE v_rcp_f32 + 2 muls.
__device__ __forceinline__ f32x2 rcp2(f32x2 a) {
    const float m = a.x * a.y;
    const float r = rcp(m);
    return (f32x2){r * a.y, r * a.x};
}

__global__ __launch_bounds__(NTHREADS, 3) void lstm_fused(
    const float* __restrict__ x,   // [B,5,1]
    const float* __restrict__ W,   // [1,256]  gate order i,f,g,o
    const float* __restrict__ U,   // [64,256]
    const float* __restrict__ b,   // [256]
    const float* __restrict__ Wd,  // [64,1]
    const float* __restrict__ bd,  // [1]
    float* __restrict__ out,       // [B,1]
    int B)
{
    __shared__ _Float16 hbuf[2][2][64 * HSTR];  // [group][parity] 34.0 KB
    __shared__ float xs[5][MB];                 // 2.5 KB, [t][row]
    __shared__ float red[2][MB];                // 1 KB
    __shared__ float wds[64];                   // 0.25 KB

    const int tid  = threadIdx.x;
    const int wv   = tid >> 6;
    const int lane = tid & 63;
    const int l15  = lane & 15;
    const int quad = lane >> 4;
    const int row0 = blockIdx.x * MB;

    // stage x transposed to [t][row]; stage Wd
    for (int i = tid; i < MB * 5; i += NTHREADS)
        xs[i % 5][i / 5] = x[row0 * 5 + i];
    if (tid < 64) wds[tid] = Wd[tid];

    const float LOG2E = 1.44269504f;
    const float gscale[4] = {-LOG2E, -LOG2E, -2.0f * LOG2E, -LOG2E};
    const float CSC = -2.0f * LOG2E;
    const f32x2 CSC2  = {CSC, CSC};
    const f32x2 NCSC2 = {-CSC, -CSC};

    // U B-fragments loaded ONCE (n = gate*64 + wv*16 + l15,
    // k = kh*32 + quad*8 + j), scaled, cvt f16, pinned vs remat.
    const int ncol = wv * 16 + l15;
    float Wf[4], bf[4];
    f16x8 Bf[4][2];
#pragma unroll
    for (int g = 0; g < 4; ++g) {
        const int n = g * 64 + ncol;
        const float s = gscale[g];
        Wf[g] = W[n] * s;
        bf[g] = b[n] * s;
#pragma unroll
        for (int kh = 0; kh < 2; ++kh) {
            f16x8 v;
#pragma unroll
            for (int j = 0; j < 8; ++j) {
                const int k = kh * 32 + quad * 8 + j;
                v[j] = (_Float16)(U[k * 256 + n] * s);
            }
            Bf[g][kh] = v;
            asm volatile("" : "+v"(Bf[g][kh]));
        }
    }

    // cell state cs = CSC * c: [group][rt][pair], pair pr covers
    // rows quad*4+2pr+{0,1}
    f32x2 cst[2][4][2];
#pragma unroll
    for (int gr = 0; gr < 2; ++gr)
#pragma unroll
        for (int a = 0; a < 4; ++a)
#pragma unroll
            for (int pr = 0; pr < 2; ++pr) cst[gr][a][pr] = (f32x2){0.f, 0.f};

    __syncthreads();  // xs visible

    // ---- t = 0 (h=0, c=0): c = i*g, h = o*tanh(c) ----
#pragma unroll
    for (int gr = 0; gr < 2; ++gr) {
#pragma unroll
        for (int rt = 0; rt < 4; ++rt) {
            const f32x4 xv = *(const f32x4*)&xs[0][gr * 64 + rt * 16 + quad * 4];
#pragma unroll
            for (int pr = 0; pr < 2; ++pr) {
                const f32x2 xp = {xv[2 * pr], xv[2 * pr + 1]};
                const f32x2 zi = fma2(xp, (f32x2){Wf[0], Wf[0]}, (f32x2){bf[0], bf[0]});
                const f32x2 zg = fma2(xp, (f32x2){Wf[2], Wf[2]}, (f32x2){bf[2], bf[2]});
                const f32x2 zo = fma2(xp, (f32x2){Wf[3], Wf[3]}, (f32x2){bf[3], bf[3]});
                const f32x2 ei = {ex2(zi.x), ex2(zi.y)};
                const f32x2 eg = {ex2(zg.x), ex2(zg.y)};
                const f32x2 eo = {ex2(zo.x), ex2(zo.y)};
                const f32x2 pq = (1.0f + ei) * (1.0f + eg);
                const f32x2 r1 = rcp2(pq);
                const f32x2 w  = fma2(eg, NCSC2, CSC2);   // CSC*(1-eg)
                const f32x2 cs = w * r1;                  // CSC * (i*g)
                cst[gr][rt][pr] = cs;
                const f32x2 ec = {ex2(cs.x), ex2(cs.y)};
                const f32x2 dn = (1.0f + eo) * (1.0f + ec);
                const f32x2 r2 = rcp2(dn);
                const f32x2 h2 = (1.0f - ec) * r2;
                const int rb = rt * 16 + quad * 4 + 2 * pr;
                hbuf[gr][0][rb * HSTR + ncol]       = (_Float16)h2.x;
                hbuf[gr][0][(rb + 1) * HSTR + ncol] = (_Float16)h2.y;
            }
        }
    }

    // ---- t = 1..4 ----
#pragma unroll
    for (int t = 1; t < 5; ++t) {
        const int src = (t + 1) & 1;
        const int dst = t & 1;
        __syncthreads();
#pragma unroll
        for (int gr = 0; gr < 2; ++gr) {
#pragma unroll
            for (int rt = 0; rt < 4; ++rt) {
                const int arow = rt * 16 + l15;   // A layout: m = lane&15
                const f16x8 a0 = *(const f16x8*)&hbuf[gr][src][arow * HSTR + quad * 8];
                const f16x8 a1 = *(const f16x8*)&hbuf[gr][src][arow * HSTR + 32 + quad * 8];
                const f32x4 xv = *(const f32x4*)&xs[t][gr * 64 + rt * 16 + quad * 4];
                const f32x2 xlo = {xv[0], xv[1]};
                const f32x2 xhi = {xv[2], xv[3]};
                f32x4 acc[4];
#pragma unroll
                for (int g = 0; g < 4; ++g) {
                    const f32x2 wg = {Wf[g], Wf[g]};
                    const f32x2 bg = {bf[g], bf[g]};
                    const f32x2 zlo = fma2(xlo, wg, bg);
                    const f32x2 zhi = fma2(xhi, wg, bg);
                    f32x4 z = {zlo.x, zlo.y, zhi.x, zhi.y};
                    z = __builtin_amdgcn_mfma_f32_16x16x32_f16(a0, Bf[g][0], z, 0, 0, 0);
                    z = __builtin_amdgcn_mfma_f32_16x16x32_f16(a1, Bf[g][1], z, 0, 0, 0);
                    acc[g] = z;
                }
#pragma unroll
                for (int pr = 0; pr < 2; ++pr) {
                    const f32x2 ei = {ex2(acc[0][2 * pr]), ex2(acc[0][2 * pr + 1])};
                    const f32x2 ef = {ex2(acc[1][2 * pr]), ex2(acc[1][2 * pr + 1])};
                    const f32x2 eg = {ex2(acc[2][2 * pr]), ex2(acc[2][2 * pr + 1])};
                    const f32x2 eo = {ex2(acc[3][2 * pr]), ex2(acc[3][2 * pr + 1])};
                    const f32x2 p  = (1.0f + ei) * (1.0f + eg);
                    const f32x2 q  = 1.0f + ef;
                    const f32x2 w  = fma2(eg, NCSC2, CSC2);          // CSC*(1-eg)
                    const f32x2 nums = fma2(cst[gr][rt][pr], p, q * w); // CSC*num
                    const f32x2 ipq  = rcp2(p * q);
                    const f32x2 cs   = nums * ipq;                   // CSC*c'
                    cst[gr][rt][pr] = cs;
                    const f32x2 ec = {ex2(cs.x), ex2(cs.y)};
                    const f32x2 dn = (1.0f + eo) * (1.0f + ec);
                    const f32x2 r2 = rcp2(dn);
                    const f32x2 h2 = (1.0f - ec) * r2;
                    const int rb = rt * 16 + quad * 4 + 2 * pr;
                    hbuf[gr][dst][rb * HSTR + ncol]       = (_Float16)h2.x;
                    hbuf[gr][dst][(rb + 1) * HSTR + ncol] = (_Float16)h2.y;
                }
            }
        }
    }

    __syncthreads();  // h(t=4) complete in hbuf[*][0]

    // Dense(1, relu): each thread sums 32 of the 64 units for one row.
    {
        const int row = tid & 127;          // 0..127
        const int qh  = tid >> 7;           // 0..1
        const int gr  = row >> 6;
        const int rl  = row & 63;
        float s = 0.0f;
#pragma unroll
        for (int j = 0; j < 32; ++j)
            s += (float)hbuf[gr][0][rl * HSTR + qh * 32 + j] * wds[qh * 32 + j];
        red[qh][row] = s;
    }
    __syncthreads();
    if (tid < MB) {
        const float r = red[0][tid] + red[1][tid] + bd[0];
        out[row0 + tid] = fmaxf(r, 0.0f);
    }
}

extern "C" void kernel_launch(void* const* d_in, const int* in_sizes, int n_in,
                              void* d_out, int out_size, void* d_ws, size_t ws_size,
                              hipStream_t stream) {
    const float* x  = (const float*)d_in[0];
    const float* W  = (const float*)d_in[1];
    const float* U  = (const float*)d_in[2];
    const float* b  = (const float*)d_in[3];
    const float* Wd = (const float*)d_in[4];
    const float* bd = (const float*)d_in[5];
    float* out = (float*)d_out;
    const int B = in_sizes[0] / 5;
    const int grid = B / MB;   // 2048 blocks
    lstm_fused<<<grid, NTHREADS, 0, stream>>>(x, W, U, b, Wd, bd, out, B);
}

// Round 2
// 133.844 us; speedup vs baseline: 1.0616x; 1.0260x over previous
//
#include <hip/hip_runtime.h>

// LSTM(units=64) over T=5, D_IN=1, then Dense(1, relu).
// R15 = R14 + issue-stream reduction (trans stream untouched):
//  (a) fma-folded gate algebra: P=1+ei; p=fma(eg,P,P); q eliminated via
//      qw=fma(ef,w,w), pq=fma(ef,p,p); dn=fma(ec,Ao,Ao).  (1+e)-products
//      cost 2 ops not 3; q's pk_add gone.
//  (b) cross-pair batched reciprocals: the tile's two pk-pairs computed
//      together; 4 recips = {m=pqA*pqB (pk); r=rcp x2; r*pqB, r*pqA (pk)}
//      = 5 issues vs 8.  Overflow safety IDENTICAL to R14's rcp2 (same
//      product-of-two-pq-scalars structure): pq<=1.3e18 -> m<=1.7e36;
//      dn<=2.4e10 -> m<=5.8e20.  Trans count unchanged.
//  Net: cell-math 24 -> 18 non-trans issues/pair (~ -12% total issue).
// R14 post-mortem: -14.7% trans ops gave only -2% wall with VALUBusy flat
// => kernel sits at trans-pipe ~= VALU-issue crossing point; must cut
// issue without adding trans (this round) -- trans is at algebraic floor
// (10 exp2 + 2 rcp per pair).
// CHAMPION structure (91.2us rocprof best at R14): MB=128 column
// partition, wave w owns gate-cols [w*16,w*16+16) of all 4 gates, U
// B-fragments register-resident (asm-pinned vs remat), barriers between
// timesteps, packed-fp32 cell pairs, cs = CSC*c carried state:
//   p=(1+ei)(1+eg), q=(1+ef):  cs' = (cs*p + q*CSC*(1-eg)) / (p*q)
//   h = (1-ec) / ((1+eo)(1+ec)),  ec = exp2(cs')
// Survey (R1-R14, counters-verified): remat fix+exp2 algebra 133->102;
// packed cell-pairs ->95.8; MB 64/128/256 = 95.8/93.0/109; occupancy
// pinned ~3 waves/SIMD (unified VGPR+AGPR); barrier-free row partition
// regressed (104); software exp2 regressed (147); paired-rcp+CSC-fold
// 93.0->91.2 (revealed issue/trans balance).
// Falsification branch: if dur flat & VALUBusy drops -> latency/convoy
// bound -> next: single-buffer hbuf + split read/write barriers for
// higher blocks/CU.
// absmax: exactly 1.953125e-3 (f16 h round-trip quantization).

typedef _Float16 f16x8 __attribute__((ext_vector_type(8)));
typedef float f32x4 __attribute__((ext_vector_type(4)));
typedef float f32x2 __attribute__((ext_vector_type(2)));

#define MB 128       // rows per block (2 groups of 64)
#define NTHREADS 256
#define HSTR 68

__device__ __forceinline__ float ex2(float x) { return __builtin_amdgcn_exp2f(x); }
__device__ __forceinline__ float rcp(float x) { return __builtin_amdgcn_rcpf(x); }
__device__ __forceinline__ f32x2 fma2(f32x2 a, f32x2 b, f32x2 c) {
    return __builtin_elementwise_fma(a, b, c);
}

__global__ __launch_bounds__(NTHREADS, 3) void lstm_fused(
    const float* __restrict__ x,   // [B,5,1]
    const float* __restrict__ W,   // [1,256]  gate order i,f,g,o
    const float* __restrict__ U,   // [64,256]
    const float* __restrict__ b,   // [256]
    const float* __restrict__ Wd,  // [64,1]
    const float* __restrict__ bd,  // [1]
    float* __restrict__ out,       // [B,1]
    int B)
{
    __shared__ _Float16 hbuf[2][2][64 * HSTR];  // [group][parity] 34.0 KB
    __shared__ float xs[5][MB];                 // 2.5 KB, [t][row]
    __shared__ float red[2][MB];                // 1 KB
    __shared__ float wds[64];                   // 0.25 KB

    const int tid  = threadIdx.x;
    const int wv   = tid >> 6;
    const int lane = tid & 63;
    const int l15  = lane & 15;
    const int quad = lane >> 4;
    const int row0 = blockIdx.x * MB;

    // stage x transposed to [t][row]; stage Wd
    for (int i = tid; i < MB * 5; i += NTHREADS)
        xs[i % 5][i / 5] = x[row0 * 5 + i];
    if (tid < 64) wds[tid] = Wd[tid];

    const float LOG2E = 1.44269504f;
    const float gscale[4] = {-LOG2E, -LOG2E, -2.0f * LOG2E, -LOG2E};
    const float CSC = -2.0f * LOG2E;
    const f32x2 CSC2  = {CSC, CSC};
    const f32x2 NCSC2 = {-CSC, -CSC};

    // U B-fragments loaded ONCE (n = gate*64 + wv*16 + l15,
    // k = kh*32 + quad*8 + j), scaled, cvt f16, pinned vs remat.
    const int ncol = wv * 16 + l15;
    float Wf[4], bf[4];
    f16x8 Bf[4][2];
#pragma unroll
    for (int g = 0; g < 4; ++g) {
        const int n = g * 64 + ncol;
        const float s = gscale[g];
        Wf[g] = W[n] * s;
        bf[g] = b[n] * s;
#pragma unroll
        for (int kh = 0; kh < 2; ++kh) {
            f16x8 v;
#pragma unroll
            for (int j = 0; j < 8; ++j) {
                const int k = kh * 32 + quad * 8 + j;
                v[j] = (_Float16)(U[k * 256 + n] * s);
            }
            Bf[g][kh] = v;
            asm volatile("" : "+v"(Bf[g][kh]));
        }
    }

    // cell state cs = CSC * c: [group][rt][pair], pair pr covers
    // rows quad*4+2pr+{0,1}
    f32x2 cst[2][4][2];
#pragma unroll
    for (int gr = 0; gr < 2; ++gr)
#pragma unroll
        for (int a = 0; a < 4; ++a)
#pragma unroll
            for (int pr = 0; pr < 2; ++pr) cst[gr][a][pr] = (f32x2){0.f, 0.f};

    __syncthreads();  // xs visible

    // ---- t = 0 (h=0, c=0): c = i*g, h = o*tanh(c) ----
#pragma unroll
    for (int gr = 0; gr < 2; ++gr) {
#pragma unroll
        for (int rt = 0; rt < 4; ++rt) {
            const f32x4 xv = *(const f32x4*)&xs[0][gr * 64 + rt * 16 + quad * 4];
            const f32x2 xp0 = {xv[0], xv[1]};
            const f32x2 xp1 = {xv[2], xv[3]};
            const f32x2 wi = {Wf[0], Wf[0]}, bi = {bf[0], bf[0]};
            const f32x2 wg = {Wf[2], Wf[2]}, bg = {bf[2], bf[2]};
            const f32x2 wo = {Wf[3], Wf[3]}, bo = {bf[3], bf[3]};
            const f32x2 zi0 = fma2(xp0, wi, bi), zi1 = fma2(xp1, wi, bi);
            const f32x2 zg0 = fma2(xp0, wg, bg), zg1 = fma2(xp1, wg, bg);
            const f32x2 zo0 = fma2(xp0, wo, bo), zo1 = fma2(xp1, wo, bo);
            const f32x2 ei0 = {ex2(zi0.x), ex2(zi0.y)};
            const f32x2 ei1 = {ex2(zi1.x), ex2(zi1.y)};
            const f32x2 eg0 = {ex2(zg0.x), ex2(zg0.y)};
            const f32x2 eg1 = {ex2(zg1.x), ex2(zg1.y)};
            const f32x2 eo0 = {ex2(zo0.x), ex2(zo0.y)};
            const f32x2 eo1 = {ex2(zo1.x), ex2(zo1.y)};
            // site1 (q=1 at t0): pq = p = (1+ei)(1+eg)
            const f32x2 P0 = ei0 + 1.0f;
            const f32x2 P1 = ei1 + 1.0f;
            const f32x2 p0 = fma2(eg0, P0, P0);
            const f32x2 p1 = fma2(eg1, P1, P1);
            const f32x2 w0 = fma2(eg0, NCSC2, CSC2);   // CSC*(1-eg)
            const f32x2 w1 = fma2(eg1, NCSC2, CSC2);
            const f32x2 m1 = p0 * p1;
            const f32x2 r1 = {rcp(m1.x), rcp(m1.y)};
            const f32x2 cs0 = w0 * (r1 * p1);          // CSC * (i*g)
            const f32x2 cs1 = w1 * (r1 * p0);
            cst[gr][rt][0] = cs0;
            cst[gr][rt][1] = cs1;
            const f32x2 ec0 = {ex2(cs0.x), ex2(cs0.y)};
            const f32x2 ec1 = {ex2(cs1.x), ex2(cs1.y)};
            const f32x2 Ao0 = eo0 + 1.0f;
            const f32x2 Ao1 = eo1 + 1.0f;
            const f32x2 dn0 = fma2(ec0, Ao0, Ao0);
            const f32x2 dn1 = fma2(ec1, Ao1, Ao1);
            const f32x2 om0 = 1.0f - ec0;
            const f32x2 om1 = 1.0f - ec1;
            const f32x2 m2 = dn0 * dn1;
            const f32x2 r2 = {rcp(m2.x), rcp(m2.y)};
            const f32x2 h20 = om0 * (r2 * dn1);
            const f32x2 h21 = om1 * (r2 * dn0);
            const int rb = rt * 16 + quad * 4;
            hbuf[gr][0][(rb + 0) * HSTR + ncol] = (_Float16)h20.x;
            hbuf[gr][0][(rb + 1) * HSTR + ncol] = (_Float16)h20.y;
            hbuf[gr][0][(rb + 2) * HSTR + ncol] = (_Float16)h21.x;
            hbuf[gr][0][(rb + 3) * HSTR + ncol] = (_Float16)h21.y;
        }
    }

    // ---- t = 1..4 ----
#pragma unroll
    for (int t = 1; t < 5; ++t) {
        const int src = (t + 1) & 1;
        const int dst = t & 1;
        __syncthreads();
#pragma unroll
        for (int gr = 0; gr < 2; ++gr) {
#pragma unroll
            for (int rt = 0; rt < 4; ++rt) {
                const int arow = rt * 16 + l15;   // A layout: m = lane&15
                const f16x8 a0 = *(const f16x8*)&hbuf[gr][src][arow * HSTR + quad * 8];
                const f16x8 a1 = *(const f16x8*)&hbuf[gr][src][arow * HSTR + 32 + quad * 8];
                const f32x4 xv = *(const f32x4*)&xs[t][gr * 64 + rt * 16 + quad * 4];
                const f32x2 xlo = {xv[0], xv[1]};
                const f32x2 xhi = {xv[2], xv[3]};
                f32x4 acc[4];
#pragma unroll
                for (int g = 0; g < 4; ++g) {
                    const f32x2 wg = {Wf[g], Wf[g]};
                    const f32x2 bg = {bf[g], bf[g]};
                    const f32x2 zlo = fma2(xlo, wg, bg);
                    const f32x2 zhi = fma2(xhi, wg, bg);
                    f32x4 z = {zlo.x, zlo.y, zhi.x, zhi.y};
                    z = __builtin_amdgcn_mfma_f32_16x16x32_f16(a0, Bf[g][0], z, 0, 0, 0);
                    z = __builtin_amdgcn_mfma_f32_16x16x32_f16(a1, Bf[g][1], z, 0, 0, 0);
                    acc[g] = z;
                }
                // dual-pair cell math (pairs pr=0 -> acc[..][0,1],
                // pr=1 -> acc[..][2,3]); batched reciprocals.
                const f32x2 ei0 = {ex2(acc[0][0]), ex2(acc[0][1])};
                const f32x2 ei1 = {ex2(acc[0][2]), ex2(acc[0][3])};
                const f32x2 ef0 = {ex2(acc[1][0]), ex2(acc[1][1])};
                const f32x2 ef1 = {ex2(acc[1][2]), ex2(acc[1][3])};
                const f32x2 eg0 = {ex2(acc[2][0]), ex2(acc[2][1])};
                const f32x2 eg1 = {ex2(acc[2][2]), ex2(acc[2][3])};
                const f32x2 eo0 = {ex2(acc[3][0]), ex2(acc[3][1])};
                const f32x2 eo1 = {ex2(acc[3][2]), ex2(acc[3][3])};
                const f32x2 P0 = ei0 + 1.0f;
                const f32x2 P1 = ei1 + 1.0f;
                const f32x2 p0 = fma2(eg0, P0, P0);        // (1+ei)(1+eg)
                const f32x2 p1 = fma2(eg1, P1, P1);
                const f32x2 w0 = fma2(eg0, NCSC2, CSC2);   // CSC*(1-eg)
                const f32x2 w1 = fma2(eg1, NCSC2, CSC2);
                const f32x2 qw0 = fma2(ef0, w0, w0);       // q*w
                const f32x2 qw1 = fma2(ef1, w1, w1);
                const f32x2 nums0 = fma2(cst[gr][rt][0], p0, qw0);  // CSC*num
                const f32x2 nums1 = fma2(cst[gr][rt][1], p1, qw1);
                const f32x2 pq0 = fma2(ef0, p0, p0);       // p*q
                const f32x2 pq1 = fma2(ef1, p1, p1);
                const f32x2 m1 = pq0 * pq1;
                const f32x2 r1 = {rcp(m1.x), rcp(m1.y)};
                const f32x2 cs0 = nums0 * (r1 * pq1);      // CSC*c'
                const f32x2 cs1 = nums1 * (r1 * pq0);
                cst[gr][rt][0] = cs0;
                cst[gr][rt][1] = cs1;
                const f32x2 ec0 = {ex2(cs0.x), ex2(cs0.y)};
                const f32x2 ec1 = {ex2(cs1.x), ex2(cs1.y)};
                const f32x2 Ao0 = eo0 + 1.0f;
                const f32x2 Ao1 = eo1 + 1.0f;
                const f32x2 dn0 = fma2(ec0, Ao0, Ao0);     // (1+eo)(1+ec)
                const f32x2 dn1 = fma2(ec1, Ao1, Ao1);
                const f32x2 om0 = 1.0f - ec0;
                const f32x2 om1 = 1.0f - ec1;
                const f32x2 m2 = dn0 * dn1;
                const f32x2 r2 = {rcp(m2.x), rcp(m2.y)};
                const f32x2 h20 = om0 * (r2 * dn1);
                const f32x2 h21 = om1 * (r2 * dn0);
                const int rb = rt * 16 + quad * 4;
                hbuf[gr][dst][(rb + 0) * HSTR + ncol] = (_Float16)h20.x;
                hbuf[gr][dst][(rb + 1) * HSTR + ncol] = (_Float16)h20.y;
                hbuf[gr][dst][(rb + 2) * HSTR + ncol] = (_Float16)h21.x;
                hbuf[gr][dst][(rb + 3) * HSTR + ncol] = (_Float16)h21.y;
            }
        }
    }

    __syncthreads();  // h(t=4) complete in hbuf[*][0]

    // Dense(1, relu): each thread sums 32 of the 64 units for one row.
    {
        const int row = tid & 127;          // 0..127
        const int qh  = tid >> 7;           // 0..1
        const int gr  = row >> 6;
        const int rl  = row & 63;
        float s = 0.0f;
#pragma unroll
        for (int j = 0; j < 32; ++j)
            s += (float)hbuf[gr][0][rl * HSTR + qh * 32 + j] * wds[qh * 32 + j];
        red[qh][row] = s;
    }
    __syncthreads();
    if (tid < MB) {
        const float r = red[0][tid] + red[1][tid] + bd[0];
        out[row0 + tid] = fmaxf(r, 0.0f);
    }
}

extern "C" void kernel_launch(void* const* d_in, const int* in_sizes, int n_in,
                              void* d_out, int out_size, void* d_ws, size_t ws_size,
                              hipStream_t stream) {
    const float* x  = (const float*)d_in[0];
    const float* W  = (const float*)d_in[1];
    const float* U  = (const float*)d_in[2];
    const float* b  = (const float*)d_in[3];
    const float* Wd = (const float*)d_in[4];
    const float* bd = (const float*)d_in[5];
    float* out = (float*)d_out;
    const int B = in_sizes[0] / 5;
    const int grid = B / MB;   // 2048 blocks
    lstm_fused<<<grid, NTHREADS, 0, stream>>>(x, W, U, b, Wd, bd, out, B);
}